// Round 4
// baseline (725.349 us; speedup 1.0000x reference)
//
#include <hip/hip_runtime.h>
#include <stdint.h>

using bf16x8 = __attribute__((ext_vector_type(8))) __bf16;
using f32x4  = __attribute__((ext_vector_type(4))) float;

#define AS1 __attribute__((address_space(1)))
#define AS3 __attribute__((address_space(3)))

// ---------------- workspace layout (bytes) ----------------
constexpr size_t OFF_WHH   = 0;                                // [1536][512] bf16
constexpr size_t OFF_WPROJ = OFF_WHH   + (size_t)1536*512*2;   // [512][512] bf16
constexpr size_t OFF_WOUT  = OFF_WPROJ + (size_t)512*512*2;    // [256][512] bf16 (padded)
constexpr size_t OFF_BHN   = OFF_WOUT  + (size_t)256*512*2;    // [512] f32
constexpr size_t OFF_BPROJ = OFF_BHN   + 512*4;
constexpr size_t OFF_BOUT  = OFF_BPROJ + 512*4;                // [256] f32 (padded)
constexpr size_t OFF_EP    = OFF_BOUT  + 256*4;                // EMBPROJ [193][1536] f32
constexpr size_t OFF_HS    = OFF_EP    + (size_t)193*1536*4;   // [15][8192][512] bf16
constexpr size_t OFF_IMG   = OFF_HS    + (size_t)15*8192*512*2;// [8192][512] bf16
constexpr size_t WS_NEED   = OFF_IMG   + (size_t)8192*512*2;   // ~137 MB

// ---------------- helpers ----------------
__device__ __forceinline__ short f2bf(float f) {
  union { float f; unsigned u; } v; v.f = f;
  unsigned u = v.u;
  u += 0x7FFFu + ((u >> 16) & 1u);   // RNE
  return (short)(u >> 16);
}
__device__ __forceinline__ float bf2f(short s) {
  union { float f; unsigned u; } v; v.u = ((unsigned)(unsigned short)s) << 16;
  return v.f;
}
__device__ __forceinline__ float sigm(float x) { return 1.f / (1.f + __expf(-x)); }
__device__ __forceinline__ float tanh_fast(float x) {
  x = fminf(fmaxf(x, -15.f), 15.f);
  float e = __expf(-2.f * x);
  return (1.f - e) / (1.f + e);
}

// Stage ROWS x 64(bf16) tile: linear LDS dest, XOR-swizzled per-lane global source
// (rule #21: linear dest + inverse-swz source + swz on read).
template<int ROWS, int WAVES>
__device__ __forceinline__ void stage_tile(const short* __restrict__ src, size_t row0,
                                           int stride, int k0, char* lds, int tid) {
  const int w = tid >> 6;
  const int lane = tid & 63;
#pragma unroll
  for (int s = 0; s < ROWS / (8 * WAVES); ++s) {
    const int rowbase = s * (8 * WAVES) + w * 8;   // wave-uniform
    const int row = rowbase + (lane >> 3);
    const int colE = ((lane & 7) ^ (row & 7)) * 8; // pre-swizzled source column
    const short* g = src + (row0 + (size_t)row) * (size_t)stride + k0 + colE;
    __builtin_amdgcn_global_load_lds((const AS1 int*)g, (AS3 int*)(lds + rowbase * 128),
                                     16, 0, 0);
  }
}

// Read a 16x32 MFMA fragment (8 bf16/lane) with the matching XOR swizzle.
__device__ __forceinline__ bf16x8 read_frag(const char* lds, int row, int ks, int lane) {
  const int kb = ks * 64 + ((lane >> 4) << 4);
  return *(const bf16x8*)(lds + row * 128 + (kb ^ ((row & 7) << 4)));
}

// ---------------- prep: pack weights/biases (bf16) ----------------
__global__ void prep_kernel(const float* __restrict__ W_proj, const float* __restrict__ b_proj,
                            const float* __restrict__ W_hh, const float* __restrict__ b_hh,
                            const float* __restrict__ W_out, const float* __restrict__ b_out,
                            short* __restrict__ whh, short* __restrict__ wproj,
                            short* __restrict__ wout,
                            float* __restrict__ bhn, float* __restrict__ bproj,
                            float* __restrict__ bout) {
  const int total = 1536*512 + 512*512 + 256*512 + 512 + 512 + 256;
  const int stride = gridDim.x * blockDim.x;
  for (int i = blockIdx.x * blockDim.x + threadIdx.x; i < total; i += stride) {
    int j = i;
    if (j < 1536*512) { whh[j] = f2bf(W_hh[j]); continue; }
    j -= 1536*512;
    if (j < 512*512) { wproj[j] = f2bf(W_proj[j]); continue; }
    j -= 512*512;
    if (j < 256*512) {
      int r = j / 512, c = j % 512;
      wout[j] = f2bf(r < 193 ? W_out[r*512 + c] : 0.f);
      continue;
    }
    j -= 256*512;
    if (j < 512) { bhn[j] = b_hh[1024 + j]; continue; }
    j -= 512;
    if (j < 512) { bproj[j] = b_proj[j]; continue; }
    j -= 512;
    bout[j] = (j < 193) ? b_out[j] : 0.f;
  }
}

// ---------------- EMBPROJ[v][c] = emb[v] . W_ih[c] + b_ih[c] (+ b_hh[c] for r,z) ----------------
__global__ void embproj_kernel(const float* __restrict__ emb, const float* __restrict__ W_ih,
                               const float* __restrict__ b_ih, const float* __restrict__ b_hh,
                               float* __restrict__ ep) {
  const int idx = blockIdx.x * blockDim.x + threadIdx.x;
  if (idx >= 193 * 1536) return;
  const int v = idx / 1536, c = idx % 1536;
  const float* er = emb + (size_t)v * 256;
  const float* wr = W_ih + (size_t)c * 256;
  float s = 0.f;
#pragma unroll 4
  for (int k = 0; k < 256; k += 4) {
    const float4 a = *(const float4*)(er + k);
    const float4 b = *(const float4*)(wr + k);
    s += a.x * b.x + a.y * b.y + a.z * b.z + a.w * b.w;
  }
  s += b_ih[c] + (c < 1024 ? b_hh[c] : 0.f);
  ep[idx] = s;
}

// ---------------- img -> bf16 ----------------
__global__ void imgcvt_kernel(const float* __restrict__ img, short* __restrict__ imgbf) {
  const int i = blockIdx.x * blockDim.x + threadIdx.x;  // 8192*128 groups of 4
  const float4 v = *(const float4*)(img + (size_t)i * 4);
  short4 o; o.x = f2bf(v.x); o.y = f2bf(v.y); o.z = f2bf(v.z); o.w = f2bf(v.w);
  *(short4*)(imgbf + (size_t)i * 4) = o;
}

// ---------------- GEMM, 8 waves (2x4), 128M x 256N tile, K=512, counted-vmcnt 2-phase ----------------
// MODE 0: h0 projection (write bf16 hs).  MODE 1: vocab out (write f32 scattered, j<193).
template<int MODE>
__global__ __launch_bounds__(512, 1)
void gemm_kernel(const short* __restrict__ A, const short* __restrict__ Bw,
                 const float* __restrict__ bias, float* __restrict__ out_f,
                 short* __restrict__ out_bf) {
  __shared__ __align__(16) char smem[2 * 49152];   // per buf: A 16K + B 32K
  const int tid = threadIdx.x;
  const int lane = tid & 63;
  const int w = tid >> 6;
  const int wr = w >> 2, wc = w & 3;   // 2x4 wave grid, wave-tile 64x64
  const size_t m0 = (size_t)blockIdx.x * 128;
  const int j0 = blockIdx.y * 256;

  f32x4 acc[4][4];
#pragma unroll
  for (int a = 0; a < 4; ++a)
#pragma unroll
    for (int b = 0; b < 4; ++b) acc[a][b] = f32x4{0.f, 0.f, 0.f, 0.f};

  auto STAGE = [&](int buf, int it) {
    const int k0 = it * 64;
    char* ldsA = smem + buf * 49152;
    char* ldsB = ldsA + 16384;
    stage_tile<128, 8>(A, m0, 512, k0, ldsA, tid);        // 2 loads/thread
    stage_tile<256, 8>(Bw, (size_t)j0, 512, k0, ldsB, tid); // 4 loads/thread
  };

  STAGE(0, 0);
  int cur = 0;
  for (int it = 0; it < 8; ++it) {
    if (it < 7) {
      STAGE(cur ^ 1, it + 1);                         // 6 new loads in flight
      asm volatile("s_waitcnt vmcnt(6)" ::: "memory"); // prior buf's 6 loads done
    } else {
      asm volatile("s_waitcnt vmcnt(0)" ::: "memory");
    }
    __builtin_amdgcn_s_barrier();                     // cur buf ready for all waves
    const char* ldsA = smem + cur * 49152;
    const char* ldsB = ldsA + 16384;
#pragma unroll
    for (int ks = 0; ks < 2; ++ks) {
      bf16x8 af[4];
#pragma unroll
      for (int mi = 0; mi < 4; ++mi)
        af[mi] = read_frag(ldsA, wr*64 + mi*16 + (lane & 15), ks, lane);
#pragma unroll
      for (int ji = 0; ji < 4; ++ji) {
        bf16x8 bfm = read_frag(ldsB, wc*64 + ji*16 + (lane & 15), ks, lane);
#pragma unroll
        for (int mi = 0; mi < 4; ++mi)
          acc[mi][ji] = __builtin_amdgcn_mfma_f32_16x16x32_bf16(af[mi], bfm, acc[mi][ji], 0, 0, 0);
      }
    }
    asm volatile("" ::: "memory");
    __builtin_amdgcn_s_barrier();                     // all reads of cur done -> next STAGE may overwrite
    cur ^= 1;
  }
#pragma unroll
  for (int ji = 0; ji < 4; ++ji) {
    const int j = j0 + wc*64 + ji*16 + (lane & 15);
    const float bj = bias[j];
#pragma unroll
    for (int mi = 0; mi < 4; ++mi) {
#pragma unroll
      for (int i = 0; i < 4; ++i) {
        const size_t m = m0 + wr*64 + mi*16 + ((lane >> 4) * 4) + i;
        const float v = acc[mi][ji][i] + bj;
        if (MODE == 0) {
          out_bf[m * 512 + j] = f2bf(v);
        } else {
          if (j < 193) {
            const size_t b = m & 8191, t = m >> 13;
            out_f[(b * 14 + t) * 193 + j] = v;
          }
        }
      }
    }
  }
}

// ---------------- fused GRU step: gh = h @ W_hh^T (K=512), x-part gathered from EMBPROJ ----------------
// acc sets: r, z, hn over K=512. Epilogue: r=sigm(acc_r+ep_r); z=sigm(acc_z+ep_z);
// n=tanh(ep_n + r*(acc_hn+bhn)); h' = (1-z)n + z h.
__global__ __launch_bounds__(256, 2)
void gate_kernel(const short* __restrict__ Hbf, const short* __restrict__ whh,
                 const int* __restrict__ text, const int t,
                 const float* __restrict__ embproj, const float* __restrict__ bhn,
                 short* __restrict__ hs_out) {
  __shared__ __align__(16) char smem[2 * 40960];   // per buf: A 16K + B(3 gates) 24K
  const int tid = threadIdx.x;
  const int lane = tid & 63;
  const int w = tid >> 6;
  const int wr = w >> 1, wc = w & 1;   // wave-tile 64M x 32N
  const size_t m0 = (size_t)blockIdx.x * 128;
  const int j0 = blockIdx.y * 64;

  f32x4 acc_r[4][2], acc_z[4][2], acc_hn[4][2];
#pragma unroll
  for (int a = 0; a < 4; ++a)
#pragma unroll
    for (int b = 0; b < 2; ++b) {
      acc_r[a][b] = f32x4{0.f, 0.f, 0.f, 0.f};
      acc_z[a][b] = f32x4{0.f, 0.f, 0.f, 0.f};
      acc_hn[a][b] = f32x4{0.f, 0.f, 0.f, 0.f};
    }

  auto STAGE = [&](int buf, int it) {
    const int k0 = it * 64;
    char* ldsA = smem + buf * 40960;
    char* ldsB = ldsA + 16384;
    stage_tile<128, 4>(Hbf, m0, 512, k0, ldsA, tid);  // 4 loads/thread
#pragma unroll
    for (int g = 0; g < 3; ++g)                       // 6 loads/thread
      stage_tile<64, 4>(whh, (size_t)(g * 512 + j0), 512, k0, ldsB + g * 8192, tid);
  };

  STAGE(0, 0);
  int cur = 0;
  for (int it = 0; it < 8; ++it) {
    if (it < 7) {
      STAGE(cur ^ 1, it + 1);                          // 10 new loads in flight
      asm volatile("s_waitcnt vmcnt(10)" ::: "memory"); // prior buf's 10 loads done
    } else {
      asm volatile("s_waitcnt vmcnt(0)" ::: "memory");
    }
    __builtin_amdgcn_s_barrier();
    const char* ldsA = smem + cur * 40960;
    const char* ldsB = ldsA + 16384;
#pragma unroll
    for (int ks = 0; ks < 2; ++ks) {
      bf16x8 af[4];
#pragma unroll
      for (int mi = 0; mi < 4; ++mi)
        af[mi] = read_frag(ldsA, wr*64 + mi*16 + (lane & 15), ks, lane);
#pragma unroll
      for (int ji = 0; ji < 2; ++ji) {
        const int nb = wc*32 + ji*16 + (lane & 15);
        bf16x8 b_r = read_frag(ldsB,         nb, ks, lane);
        bf16x8 b_z = read_frag(ldsB + 8192,  nb, ks, lane);
        bf16x8 b_n = read_frag(ldsB + 16384, nb, ks, lane);
#pragma unroll
        for (int mi = 0; mi < 4; ++mi) {
          acc_r[mi][ji]  = __builtin_amdgcn_mfma_f32_16x16x32_bf16(af[mi], b_r, acc_r[mi][ji], 0, 0, 0);
          acc_z[mi][ji]  = __builtin_amdgcn_mfma_f32_16x16x32_bf16(af[mi], b_z, acc_z[mi][ji], 0, 0, 0);
          acc_hn[mi][ji] = __builtin_amdgcn_mfma_f32_16x16x32_bf16(af[mi], b_n, acc_hn[mi][ji], 0, 0, 0);
        }
      }
    }
    asm volatile("" ::: "memory");
    __builtin_amdgcn_s_barrier();
    cur ^= 1;
  }
  // epilogue: gather EMBPROJ[token] + gate math + h update
  int toks[4][4];
#pragma unroll
  for (int mi = 0; mi < 4; ++mi)
#pragma unroll
    for (int i = 0; i < 4; ++i) {
      const size_t m = m0 + wr*64 + mi*16 + ((lane >> 4) * 4) + i;
      toks[mi][i] = text[m * 15 + t];
    }
#pragma unroll
  for (int ji = 0; ji < 2; ++ji) {
    const int j = j0 + wc*32 + ji*16 + (lane & 15);
    const float vbhn = bhn[j];
#pragma unroll
    for (int mi = 0; mi < 4; ++mi) {
#pragma unroll
      for (int i = 0; i < 4; ++i) {
        const size_t m = m0 + wr*64 + mi*16 + ((lane >> 4) * 4) + i;
        const float* ep = embproj + (size_t)toks[mi][i] * 1536;
        const float r = sigm(acc_r[mi][ji][i] + ep[j]);
        const float z = sigm(acc_z[mi][ji][i] + ep[512 + j]);
        const float n = tanh_fast(ep[1024 + j] + r * (acc_hn[mi][ji][i] + vbhn));
        const float hold = bf2f(Hbf[m * 512 + j]);
        hs_out[m * 512 + j] = f2bf((1.f - z) * n + z * hold);
      }
    }
  }
}

// ---------------- launch ----------------
extern "C" void kernel_launch(void* const* d_in, const int* in_sizes, int n_in,
                              void* d_out, int out_size, void* d_ws, size_t ws_size,
                              hipStream_t stream) {
  (void)in_sizes; (void)n_in; (void)out_size;
  if (ws_size < WS_NEED) return;

  const float* img    = (const float*)d_in[0];
  const int*   text   = (const int*)  d_in[1];
  const float* emb    = (const float*)d_in[2];
  const float* W_proj = (const float*)d_in[3];
  const float* b_proj = (const float*)d_in[4];
  const float* W_ih   = (const float*)d_in[5];
  const float* W_hh   = (const float*)d_in[6];
  const float* b_ih   = (const float*)d_in[7];
  const float* b_hh   = (const float*)d_in[8];
  const float* W_out  = (const float*)d_in[9];
  const float* b_out  = (const float*)d_in[10];
  float* out = (float*)d_out;
  char* ws = (char*)d_ws;

  short* whh   = (short*)(ws + OFF_WHH);
  short* wproj = (short*)(ws + OFF_WPROJ);
  short* wout  = (short*)(ws + OFF_WOUT);
  float* bhn   = (float*)(ws + OFF_BHN);
  float* bproj = (float*)(ws + OFF_BPROJ);
  float* bout  = (float*)(ws + OFF_BOUT);
  float* ep    = (float*)(ws + OFF_EP);
  short* hs    = (short*)(ws + OFF_HS);
  short* imgbf = (short*)(ws + OFF_IMG);

  prep_kernel<<<512, 256, 0, stream>>>(W_proj, b_proj, W_hh, b_hh, W_out, b_out,
                                       whh, wproj, wout, bhn, bproj, bout);
  imgcvt_kernel<<<4096, 256, 0, stream>>>(img, imgbf);
  embproj_kernel<<<(193*1536 + 255)/256, 256, 0, stream>>>(emb, W_ih, b_ih, b_hh, ep);

  // h0 = img @ W_proj^T + b_proj  -> hs[0] (bf16); N=512 via 2 j-tiles of 256
  gemm_kernel<0><<<dim3(64, 2), 512, 0, stream>>>(imgbf, wproj, bproj, nullptr, hs);

  for (int t = 0; t < 14; ++t) {
    const short* Hb = hs + (size_t)t * 8192 * 512;
    short* Ho       = hs + (size_t)(t + 1) * 8192 * 512;
    gate_kernel<<<dim3(64, 8), 256, 0, stream>>>(Hb, whh, text, t, ep, bhn, Ho);
  }

  // preds = hs[1..14] @ W_out^T + b_out  -> out[b][t][v]; single N-pass (256 padded)
  gemm_kernel<1><<<dim3(896, 1), 512, 0, stream>>>(hs + (size_t)8192 * 512, wout, bout,
                                                   out, nullptr);
}

// Round 5
// 419.181 us; speedup vs baseline: 1.7304x; 1.7304x over previous
//
#include <hip/hip_runtime.h>
#include <stdint.h>

using bf16x8 = __attribute__((ext_vector_type(8))) __bf16;
using f32x4  = __attribute__((ext_vector_type(4))) float;

#define AS1 __attribute__((address_space(1)))
#define AS3 __attribute__((address_space(3)))

// ---------------- workspace layout (bytes) ----------------
constexpr size_t OFF_WHH   = 0;                                // [1536][512] bf16
constexpr size_t OFF_WPROJ = OFF_WHH   + (size_t)1536*512*2;   // [512][512] bf16
constexpr size_t OFF_WOUT  = OFF_WPROJ + (size_t)512*512*2;    // [256][512] bf16 (padded)
constexpr size_t OFF_BHN   = OFF_WOUT  + (size_t)256*512*2;    // [512] f32
constexpr size_t OFF_BPROJ = OFF_BHN   + 512*4;
constexpr size_t OFF_BOUT  = OFF_BPROJ + 512*4;                // [256] f32 (padded)
constexpr size_t OFF_EP    = OFF_BOUT  + 256*4;                // EMBPROJ [193][1536] f32
constexpr size_t OFF_HS    = OFF_EP    + (size_t)193*1536*4;   // [15][8192][512] bf16
constexpr size_t OFF_IMG   = OFF_HS    + (size_t)15*8192*512*2;// [8192][512] bf16
constexpr size_t WS_NEED   = OFF_IMG   + (size_t)8192*512*2;   // ~137 MB

// ---------------- helpers ----------------
__device__ __forceinline__ short f2bf(float f) {
  union { float f; unsigned u; } v; v.f = f;
  unsigned u = v.u;
  u += 0x7FFFu + ((u >> 16) & 1u);   // RNE
  return (short)(u >> 16);
}
__device__ __forceinline__ float bf2f(short s) {
  union { float f; unsigned u; } v; v.u = ((unsigned)(unsigned short)s) << 16;
  return v.f;
}
__device__ __forceinline__ float sigm(float x) { return 1.f / (1.f + __expf(-x)); }
__device__ __forceinline__ float tanh_fast(float x) {
  x = fminf(fmaxf(x, -15.f), 15.f);
  float e = __expf(-2.f * x);
  return (1.f - e) / (1.f + e);
}

// Stage ROWS x 64(bf16) tile: linear LDS dest, XOR-swizzled per-lane global source
// (rule #21: linear dest + inverse-swz source + swz on read).
template<int ROWS, int WAVES>
__device__ __forceinline__ void stage_tile(const short* __restrict__ src, size_t row0,
                                           int stride, int k0, char* lds, int tid) {
  const int w = tid >> 6;
  const int lane = tid & 63;
#pragma unroll
  for (int s = 0; s < ROWS / (8 * WAVES); ++s) {
    const int rowbase = s * (8 * WAVES) + w * 8;   // wave-uniform
    const int row = rowbase + (lane >> 3);
    const int colE = ((lane & 7) ^ (row & 7)) * 8; // pre-swizzled source column
    const short* g = src + (row0 + (size_t)row) * (size_t)stride + k0 + colE;
    __builtin_amdgcn_global_load_lds((const AS1 int*)g, (AS3 int*)(lds + rowbase * 128),
                                     16, 0, 0);
  }
}

// Read a 16x32 MFMA fragment (8 bf16/lane) with the matching XOR swizzle.
__device__ __forceinline__ bf16x8 read_frag(const char* lds, int row, int ks, int lane) {
  const int kb = ks * 64 + ((lane >> 4) << 4);
  return *(const bf16x8*)(lds + row * 128 + (kb ^ ((row & 7) << 4)));
}

// ---------------- prep: pack weights/biases (bf16) ----------------
__global__ void prep_kernel(const float* __restrict__ W_proj, const float* __restrict__ b_proj,
                            const float* __restrict__ W_hh, const float* __restrict__ b_hh,
                            const float* __restrict__ W_out, const float* __restrict__ b_out,
                            short* __restrict__ whh, short* __restrict__ wproj,
                            short* __restrict__ wout,
                            float* __restrict__ bhn, float* __restrict__ bproj,
                            float* __restrict__ bout) {
  const int total = 1536*512 + 512*512 + 256*512 + 512 + 512 + 256;
  const int stride = gridDim.x * blockDim.x;
  for (int i = blockIdx.x * blockDim.x + threadIdx.x; i < total; i += stride) {
    int j = i;
    if (j < 1536*512) { whh[j] = f2bf(W_hh[j]); continue; }
    j -= 1536*512;
    if (j < 512*512) { wproj[j] = f2bf(W_proj[j]); continue; }
    j -= 512*512;
    if (j < 256*512) {
      int r = j / 512, c = j % 512;
      wout[j] = f2bf(r < 193 ? W_out[r*512 + c] : 0.f);
      continue;
    }
    j -= 256*512;
    if (j < 512) { bhn[j] = b_hh[1024 + j]; continue; }
    j -= 512;
    if (j < 512) { bproj[j] = b_proj[j]; continue; }
    j -= 512;
    bout[j] = (j < 193) ? b_out[j] : 0.f;
  }
}

// ---------------- EMBPROJ[v][c] = emb[v] . W_ih[c] + b_ih[c] (+ b_hh[c] for r,z) ----------------
__global__ void embproj_kernel(const float* __restrict__ emb, const float* __restrict__ W_ih,
                               const float* __restrict__ b_ih, const float* __restrict__ b_hh,
                               float* __restrict__ ep) {
  const int idx = blockIdx.x * blockDim.x + threadIdx.x;
  if (idx >= 193 * 1536) return;
  const int v = idx / 1536, c = idx % 1536;
  const float* er = emb + (size_t)v * 256;
  const float* wr = W_ih + (size_t)c * 256;
  float s = 0.f;
#pragma unroll 4
  for (int k = 0; k < 256; k += 4) {
    const float4 a = *(const float4*)(er + k);
    const float4 b = *(const float4*)(wr + k);
    s += a.x * b.x + a.y * b.y + a.z * b.z + a.w * b.w;
  }
  s += b_ih[c] + (c < 1024 ? b_hh[c] : 0.f);
  ep[idx] = s;
}

// ---------------- img -> bf16 ----------------
__global__ void imgcvt_kernel(const float* __restrict__ img, short* __restrict__ imgbf) {
  const int i = blockIdx.x * blockDim.x + threadIdx.x;  // 8192*128 groups of 4
  const float4 v = *(const float4*)(img + (size_t)i * 4);
  short4 o; o.x = f2bf(v.x); o.y = f2bf(v.y); o.z = f2bf(v.z); o.w = f2bf(v.w);
  *(short4*)(imgbf + (size_t)i * 4) = o;
}

// ---------------- GEMM, 8 waves (2x4), 128M x 256N tile, K=512 ----------------
// MODE 0: h0 projection. A=imgbf (linear rows), write bf16 hs[0][m][j].
// MODE 1: vocab out. M is b-major (m = b*14 + t); A row = hs1[t*8192 + b];
//         writes f32 out[m*193 + j] (fully contiguous across the tile).
template<int MODE>
__global__ __launch_bounds__(512, 1)
void gemm_kernel(const short* __restrict__ A, const short* __restrict__ Bw,
                 const float* __restrict__ bias, float* __restrict__ out_f,
                 short* __restrict__ out_bf) {
  __shared__ __align__(16) char smem[49152];   // A 16K + B 32K
  char* ldsA = smem;
  char* ldsB = smem + 16384;
  const int tid = threadIdx.x;
  const int lane = tid & 63;
  const int w = tid >> 6;
  const int wr = w >> 2, wc = w & 3;   // 2x4 wave grid, wave-tile 64x64
  const unsigned m0 = blockIdx.x * 128;
  const int j0 = blockIdx.y * 256;

  f32x4 acc[4][4];
#pragma unroll
  for (int a = 0; a < 4; ++a)
#pragma unroll
    for (int b = 0; b < 4; ++b) acc[a][b] = f32x4{0.f, 0.f, 0.f, 0.f};

  for (int it = 0; it < 8; ++it) {
    const int k0 = it * 64;
    __syncthreads();
    if (MODE == 0) {
      stage_tile<128, 8>(A, m0, 512, k0, ldsA, tid);
    } else {
      // b-major A rows: row r -> m=m0+r -> (b=m/14, t=m%14) -> hs1[t*8192+b]
#pragma unroll
      for (int s = 0; s < 2; ++s) {
        const int rowbase = s * 64 + w * 8;
        const int row = rowbase + (lane >> 3);
        const unsigned m = m0 + row;
        const unsigned b = m / 14u, t = m - b * 14u;
        const int colE = ((lane & 7) ^ (row & 7)) * 8;
        const short* g = A + ((size_t)t * 8192 + b) * 512 + k0 + colE;
        __builtin_amdgcn_global_load_lds((const AS1 int*)g, (AS3 int*)(ldsA + rowbase * 128),
                                         16, 0, 0);
      }
    }
    stage_tile<256, 8>(Bw, (size_t)j0, 512, k0, ldsB, tid);
    __syncthreads();
#pragma unroll
    for (int ks = 0; ks < 2; ++ks) {
      bf16x8 af[4];
#pragma unroll
      for (int mi = 0; mi < 4; ++mi)
        af[mi] = read_frag(ldsA, wr*64 + mi*16 + (lane & 15), ks, lane);
#pragma unroll
      for (int ji = 0; ji < 4; ++ji) {
        bf16x8 bfm = read_frag(ldsB, wc*64 + ji*16 + (lane & 15), ks, lane);
#pragma unroll
        for (int mi = 0; mi < 4; ++mi)
          acc[mi][ji] = __builtin_amdgcn_mfma_f32_16x16x32_bf16(af[mi], bfm, acc[mi][ji], 0, 0, 0);
      }
    }
  }
#pragma unroll
  for (int ji = 0; ji < 4; ++ji) {
    const int j = j0 + wc*64 + ji*16 + (lane & 15);
    const float bj = bias[j];
#pragma unroll
    for (int mi = 0; mi < 4; ++mi) {
#pragma unroll
      for (int i = 0; i < 4; ++i) {
        const size_t m = m0 + wr*64 + mi*16 + ((lane >> 4) * 4) + i;
        const float v = acc[mi][ji][i] + bj;
        if (MODE == 0) {
          out_bf[m * 512 + j] = f2bf(v);
        } else {
          if (j < 193) out_f[m * 193 + j] = v;   // m is b-major bt index: contiguous
        }
      }
    }
  }
}

// ---------------- fused GRU step: gh = h @ W_hh^T (K=512), x-part gathered from EMBPROJ ----------------
// Round-2-proven loop shape: single LDS buffer, sync; stage; sync; compute.
// Epilogue: r=sigm(acc_r+ep_r); z=sigm(acc_z+ep_z); n=tanh(ep_n + r*(acc_hn+bhn));
//           h' = (1-z)n + z h.
__global__ __launch_bounds__(256, 2)
void gate_kernel(const short* __restrict__ Hbf, const short* __restrict__ whh,
                 const int* __restrict__ text, const int t,
                 const float* __restrict__ embproj, const float* __restrict__ bhn,
                 short* __restrict__ hs_out) {
  __shared__ __align__(16) char smem[40960];   // A 16K + B(3 gates) 24K
  char* ldsA = smem;
  char* ldsB = smem + 16384;
  const int tid = threadIdx.x;
  const int lane = tid & 63;
  const int w = tid >> 6;
  const int wr = w >> 1, wc = w & 1;   // wave-tile 64M x 32N
  const size_t m0 = (size_t)blockIdx.x * 128;
  const int j0 = blockIdx.y * 64;

  f32x4 acc_r[4][2], acc_z[4][2], acc_hn[4][2];
#pragma unroll
  for (int a = 0; a < 4; ++a)
#pragma unroll
    for (int b = 0; b < 2; ++b) {
      acc_r[a][b] = f32x4{0.f, 0.f, 0.f, 0.f};
      acc_z[a][b] = f32x4{0.f, 0.f, 0.f, 0.f};
      acc_hn[a][b] = f32x4{0.f, 0.f, 0.f, 0.f};
    }

  for (int it = 0; it < 8; ++it) {
    const int k0 = it * 64;
    __syncthreads();
    stage_tile<128, 4>(Hbf, m0, 512, k0, ldsA, tid);
#pragma unroll
    for (int g = 0; g < 3; ++g)
      stage_tile<64, 4>(whh, (size_t)(g * 512 + j0), 512, k0, ldsB + g * 8192, tid);
    __syncthreads();
#pragma unroll
    for (int ks = 0; ks < 2; ++ks) {
      bf16x8 af[4];
#pragma unroll
      for (int mi = 0; mi < 4; ++mi)
        af[mi] = read_frag(ldsA, wr*64 + mi*16 + (lane & 15), ks, lane);
#pragma unroll
      for (int ji = 0; ji < 2; ++ji) {
        const int nb = wc*32 + ji*16 + (lane & 15);
        bf16x8 b_r = read_frag(ldsB,         nb, ks, lane);
        bf16x8 b_z = read_frag(ldsB + 8192,  nb, ks, lane);
        bf16x8 b_n = read_frag(ldsB + 16384, nb, ks, lane);
#pragma unroll
        for (int mi = 0; mi < 4; ++mi) {
          acc_r[mi][ji]  = __builtin_amdgcn_mfma_f32_16x16x32_bf16(af[mi], b_r, acc_r[mi][ji], 0, 0, 0);
          acc_z[mi][ji]  = __builtin_amdgcn_mfma_f32_16x16x32_bf16(af[mi], b_z, acc_z[mi][ji], 0, 0, 0);
          acc_hn[mi][ji] = __builtin_amdgcn_mfma_f32_16x16x32_bf16(af[mi], b_n, acc_hn[mi][ji], 0, 0, 0);
        }
      }
    }
  }
  // epilogue: gather EMBPROJ[token] + gate math + h update
  int toks[4][4];
#pragma unroll
  for (int mi = 0; mi < 4; ++mi)
#pragma unroll
    for (int i = 0; i < 4; ++i) {
      const size_t m = m0 + wr*64 + mi*16 + ((lane >> 4) * 4) + i;
      toks[mi][i] = text[m * 15 + t];
    }
#pragma unroll
  for (int ji = 0; ji < 2; ++ji) {
    const int j = j0 + wc*32 + ji*16 + (lane & 15);
    const float vbhn = bhn[j];
#pragma unroll
    for (int mi = 0; mi < 4; ++mi) {
#pragma unroll
      for (int i = 0; i < 4; ++i) {
        const size_t m = m0 + wr*64 + mi*16 + ((lane >> 4) * 4) + i;
        const float* ep = embproj + (size_t)toks[mi][i] * 1536;
        const float r = sigm(acc_r[mi][ji][i] + ep[j]);
        const float z = sigm(acc_z[mi][ji][i] + ep[512 + j]);
        const float n = tanh_fast(ep[1024 + j] + r * (acc_hn[mi][ji][i] + vbhn));
        const float hold = bf2f(Hbf[m * 512 + j]);
        hs_out[m * 512 + j] = f2bf((1.f - z) * n + z * hold);
      }
    }
  }
}

// ---------------- launch ----------------
extern "C" void kernel_launch(void* const* d_in, const int* in_sizes, int n_in,
                              void* d_out, int out_size, void* d_ws, size_t ws_size,
                              hipStream_t stream) {
  (void)in_sizes; (void)n_in; (void)out_size;
  if (ws_size < WS_NEED) return;

  const float* img    = (const float*)d_in[0];
  const int*   text   = (const int*)  d_in[1];
  const float* emb    = (const float*)d_in[2];
  const float* W_proj = (const float*)d_in[3];
  const float* b_proj = (const float*)d_in[4];
  const float* W_ih   = (const float*)d_in[5];
  const float* W_hh   = (const float*)d_in[6];
  const float* b_ih   = (const float*)d_in[7];
  const float* b_hh   = (const float*)d_in[8];
  const float* W_out  = (const float*)d_in[9];
  const float* b_out  = (const float*)d_in[10];
  float* out = (float*)d_out;
  char* ws = (char*)d_ws;

  short* whh   = (short*)(ws + OFF_WHH);
  short* wproj = (short*)(ws + OFF_WPROJ);
  short* wout  = (short*)(ws + OFF_WOUT);
  float* bhn   = (float*)(ws + OFF_BHN);
  float* bproj = (float*)(ws + OFF_BPROJ);
  float* bout  = (float*)(ws + OFF_BOUT);
  float* ep    = (float*)(ws + OFF_EP);
  short* hs    = (short*)(ws + OFF_HS);
  short* imgbf = (short*)(ws + OFF_IMG);

  prep_kernel<<<512, 256, 0, stream>>>(W_proj, b_proj, W_hh, b_hh, W_out, b_out,
                                       whh, wproj, wout, bhn, bproj, bout);
  imgcvt_kernel<<<4096, 256, 0, stream>>>(img, imgbf);
  embproj_kernel<<<(193*1536 + 255)/256, 256, 0, stream>>>(emb, W_ih, b_ih, b_hh, ep);

  // h0 = img @ W_proj^T + b_proj  -> hs[0] (bf16); N=512 via 2 j-tiles of 256
  gemm_kernel<0><<<dim3(64, 2), 512, 0, stream>>>(imgbf, wproj, bproj, nullptr, hs);

  for (int t = 0; t < 14; ++t) {
    const short* Hb = hs + (size_t)t * 8192 * 512;
    short* Ho       = hs + (size_t)(t + 1) * 8192 * 512;
    gate_kernel<<<dim3(64, 8), 256, 0, stream>>>(Hb, whh, text, t, ep, bhn, Ho);
  }

  // preds: b-major M (m = b*14+t), A = hs slab starting at t=1
  gemm_kernel<1><<<dim3(896, 1), 512, 0, stream>>>(hs + (size_t)8192 * 512, wout, bout,
                                                   out, nullptr);
}